// Round 5
// baseline (483.879 us; speedup 1.0000x reference)
//
#include <hip/hip_runtime.h>

// Problem constants
static constexpr int   Cc  = 21;
static constexpr int   HWn = 512 * 512;         // 262144 = 2^18
static constexpr int   Nn  = 8 * HWn;           // 2097152 pixels
static constexpr float MAXM  = 0.5f;
static constexpr float Sc    = 30.0f;
static constexpr float LOG2E = 1.4426950408889634f;
static constexpr float LN2   = 0.6931471805599453f;

static constexpr int HIST_BLOCKS  = 512;              // 512 blk * 256 thr * 4 int4 = Nn/4
static constexpr int PXB          = 512;              // pixels per loss block (256 thr * 2 px)
static constexpr int LOSS_BLOCKS  = Nn / PXB;         // 4096

// ws layout (bytes): 0: int counts[21] ; 96: uint done-flag ; 128: double partial[4096]
static constexpr int WS_COUNTS = 0;
static constexpr int WS_FLAG   = 96;
static constexpr int WS_PART   = 128;

// ---------------------------------------------------------------------------
// K1: class histogram. Per-WAVE LDS sub-histograms, then 21 global atomics
// per block (512-deep per address — negligible tail).
__global__ __launch_bounds__(256) void hist_kernel(const int4* __restrict__ t4,
                                                   int* __restrict__ counts) {
    __shared__ int lh[4][Cc];
    int t = threadIdx.x;
    if (t < 4 * Cc) ((int*)lh)[t] = 0;
    __syncthreads();
    int wave = t >> 6;
    int base = blockIdx.x * (256 * 4) + t;
    #pragma unroll
    for (int i = 0; i < 4; ++i) {
        int4 v = t4[base + i * 256];
        atomicAdd(&lh[wave][v.x], 1);
        atomicAdd(&lh[wave][v.y], 1);
        atomicAdd(&lh[wave][v.z], 1);
        atomicAdd(&lh[wave][v.w], 1);
    }
    __syncthreads();
    if (t < Cc)
        atomicAdd(&counts[t], lh[0][t] + lh[1][t] + lh[2][t] + lh[3][t]);
}

// ---------------------------------------------------------------------------
// Async global->LDS DMA, 16 bytes per lane. LDS dest is WAVE-UNIFORM base;
// hardware writes lane L at base + L*16. Global src is per-lane.
__device__ __forceinline__ void gl_lds16(const float* g, float* l) {
    __builtin_amdgcn_global_load_lds(
        (const __attribute__((address_space(1))) void*)g,
        (__attribute__((address_space(3))) void*)l,
        16, 0, 0);
}

// ---------------------------------------------------------------------------
// K2: main loss. Rounds 1-4 proved the compiler serializes the 21-way
// register gather no matter how it's written (VGPR 24/36/60/76 all land at
// 150-190us; effective in-flight bytes/CU ~1.7KB). Fix: stage the block's
// [21][512] pred tile into LDS with global_load_lds DMA — MLP is structural
// (42 async 1KB instructions in flight, compiler can't shrink or remat),
// then run the proven two-pass softmax math from LDS. 42KB LDS -> 3
// blocks/CU; cross-block TLP overlaps one block's DMA drain with others'
// compute. m_list fused per-wave via shuffles (runs while DMA flies).
// Plain-store partials + fenced last-block-done final mean.
__global__ __launch_bounds__(256) void loss_kernel(const float* __restrict__ pred,
                                                   const int* __restrict__ target,
                                                   const int* __restrict__ counts,
                                                   double* __restrict__ partial,
                                                   unsigned int* __restrict__ flag,
                                                   float* __restrict__ out) {
    __shared__ float  sx[Cc * PXB];           // 43008 B: class-major tile
    __shared__ double wsum[4];
    __shared__ bool   s_last;
    int t    = threadIdx.x;
    int lane = t & 63;
    int wave = t >> 6;

    int n0  = blockIdx.x * PXB;               // first pixel of block
    int b   = n0 >> 18;                       // HWn = 2^18; block never straddles b
    int hw0 = n0 & (HWn - 1);
    const float* base = pred + (size_t)b * (Cc * HWn) + hw0;

    // stage: 42 DMA instructions (1KB each: 64 lanes x 16B), wave w takes
    // i = w, w+4, ... ; c and chunk are wave-uniform per instruction.
    for (int i = wave; i < 2 * Cc; i += 4) {
        int c = i >> 1, chunk = i & 1;
        const float* g = base + (size_t)c * HWn + chunk * 256 + lane * 4;
        float*       l = &sx[c * PXB + chunk * 256];   // uniform; HW adds lane*16B
        gl_lds16(g, l);
    }

    // m_list while DMA is in flight: smv = S*log2e * m_list[c] in lane c
    float mval = 0.0f;
    if (lane < Cc) {
        float cnt = (float)counts[lane] + 1e-4f;
        mval = 1.0f / sqrtf(sqrtf(cnt));      // x^-0.25, same expr as reference
    }
    float mxm = mval;
    #pragma unroll
    for (int o = 32; o >= 1; o >>= 1) mxm = fmaxf(mxm, __shfl_down(mxm, o));
    mxm = __shfl(mxm, 0);
    float smv = Sc * LOG2E * mval * (MAXM / mxm);

    // targets for this thread's two pixels (8B aligned: n0 + 2t is even)
    int2 y2 = *(const int2*)&target[n0 + 2 * t];
    float smy0 = __shfl(smv, y2.x);
    float smy1 = __shfl(smv, y2.y);

    asm volatile("s_waitcnt vmcnt(0)" ::: "memory");   // DMA drained
    __syncthreads();

    const float S2 = Sc * LOG2E;

    // pass 1: max + target value (base-2 logits) from LDS
    float mx0 = -1e30f, mx1 = -1e30f, vy0 = 0.0f, vy1 = 0.0f;
    #pragma unroll
    for (int c = 0; c < Cc; ++c) {
        float2 v = *(const float2*)&sx[c * PXB + 2 * t];
        bool  i0 = (c == y2.x), i1 = (c == y2.y);
        float a0 = fmaf(S2, v.x, i0 ? -smy0 : 0.0f);
        float a1 = fmaf(S2, v.y, i1 ? -smy1 : 0.0f);
        mx0 = fmaxf(mx0, a0); mx1 = fmaxf(mx1, a1);
        vy0 = i0 ? a0 : vy0;  vy1 = i1 ? a1 : vy1;
    }

    // pass 2: sum of exp2, re-read from LDS (cheap: ~12cy, latency hidden)
    float cb0 = -mx0, cy0 = -smy0 - mx0;
    float cb1 = -mx1, cy1 = -smy1 - mx1;
    float s0 = 0.0f, s1 = 0.0f;
    #pragma unroll
    for (int c = 0; c < Cc; ++c) {
        float2 v = *(const float2*)&sx[c * PXB + 2 * t];
        s0 += exp2f(fmaf(S2, v.x, (c == y2.x) ? cy0 : cb0));
        s1 += exp2f(fmaf(S2, v.y, (c == y2.y) ? cy1 : cb1));
    }
    float nll = (__log2f(s0) + mx0 - vy0 + __log2f(s1) + mx1 - vy1) * LN2;

    // wave (64-lane) reduce
    #pragma unroll
    for (int o = 32; o >= 1; o >>= 1) nll += __shfl_down(nll, o);

    if (lane == 0) wsum[wave] = (double)nll;
    __syncthreads();
    if (t == 0) {
        double bsum = wsum[0] + wsum[1] + wsum[2] + wsum[3];
        partial[blockIdx.x] = bsum;           // plain store, no contention
        __threadfence();                      // release partial before flag bump
        unsigned done = atomicAdd(flag, 1u);
        s_last = (done == (unsigned)(LOSS_BLOCKS - 1));
    }
    __syncthreads();

    if (s_last) {
        __threadfence();                      // acquire other blocks' partials
        double sm = 0.0;
        for (int i = t; i < LOSS_BLOCKS; i += 256) sm += partial[i];
        #pragma unroll
        for (int o = 32; o >= 1; o >>= 1) sm += __shfl_down(sm, o);
        if ((t & 63) == 0) wsum[t >> 6] = sm;
        __syncthreads();
        if (t == 0)
            out[0] = (float)((wsum[0] + wsum[1] + wsum[2] + wsum[3]) / (double)Nn);
    }
}

extern "C" void kernel_launch(void* const* d_in, const int* in_sizes, int n_in,
                              void* d_out, int out_size, void* d_ws, size_t ws_size,
                              hipStream_t stream) {
    const float* pred   = (const float*)d_in[0];
    const int*   target = (const int*)d_in[1];
    float*       out    = (float*)d_out;

    char* ws = (char*)d_ws;
    int*          counts  = (int*)(ws + WS_COUNTS);
    unsigned int* flag    = (unsigned int*)(ws + WS_FLAG);
    double*       partial = (double*)(ws + WS_PART);

    hipMemsetAsync(d_ws, 0, 128, stream);     // zero counts + done-flag

    hist_kernel <<<HIST_BLOCKS, 256, 0, stream>>>((const int4*)target, counts);
    loss_kernel <<<LOSS_BLOCKS, 256, 0, stream>>>(pred, target,
                                                  counts, partial, flag, out);
}

// Round 6
// 328.438 us; speedup vs baseline: 1.4733x; 1.4733x over previous
//
#include <hip/hip_runtime.h>

// Problem constants
static constexpr int   Cc  = 21;
static constexpr int   HWn = 512 * 512;         // 262144 = 2^18
static constexpr int   Nn  = 8 * HWn;           // 2097152 pixels
static constexpr float MAXM  = 0.5f;
static constexpr float Sc    = 30.0f;
static constexpr float LOG2E = 1.4426950408889634f;
static constexpr float LN2   = 0.6931471805599453f;

static constexpr int HIST_BLOCKS = 512;               // 512 blk * 256 thr * 4 int4 = Nn/4
static constexpr int LOSS_BLOCKS = Nn / 4 / 256;      // 2048

// ws layout (bytes): 0: int counts[21] ; 96: uint done-flag ;
//                    128: float sm2[21] ; 256: double partial[2048]
static constexpr int WS_COUNTS = 0;
static constexpr int WS_FLAG   = 96;
static constexpr int WS_SM     = 128;
static constexpr int WS_PART   = 256;

// ---------------------------------------------------------------------------
// K1: class histogram. 512 blocks (4 int4 per thread). Per-WAVE LDS
// sub-histograms, then 21 global atomics per block (512-deep per address —
// vs round-0's 2048-deep tail).
__global__ __launch_bounds__(256) void hist_kernel(const int4* __restrict__ t4,
                                                   int* __restrict__ counts) {
    __shared__ int lh[4][Cc];
    int t = threadIdx.x;
    if (t < 4 * Cc) ((int*)lh)[t] = 0;
    __syncthreads();
    int wave = t >> 6;
    int base = blockIdx.x * (256 * 4) + t;
    #pragma unroll
    for (int i = 0; i < 4; ++i) {
        int4 v = t4[base + i * 256];
        atomicAdd(&lh[wave][v.x], 1);
        atomicAdd(&lh[wave][v.y], 1);
        atomicAdd(&lh[wave][v.z], 1);
        atomicAdd(&lh[wave][v.w], 1);
    }
    __syncthreads();
    if (t < Cc)
        atomicAdd(&counts[t], lh[0][t] + lh[1][t] + lh[2][t] + lh[3][t]);
}

// ---------------------------------------------------------------------------
// K2: m_list = (counts + 1e-4)^(-1/4); m_list *= MAX_M / max(m_list);
// sm2[c] = S * m_list[c] * LOG2E (margin in base-2 logit domain).
// Off the hot path, as in round 0 — in-kernel shuffle variants cost 60us.
__global__ __launch_bounds__(64) void mlist_kernel(const int* __restrict__ counts,
                                                   float* __restrict__ sm2) {
    int t = threadIdx.x;
    float mval = 0.0f;
    if (t < Cc) {
        float cnt = (float)counts[t] + 1e-4f;
        mval = 1.0f / sqrtf(sqrtf(cnt));      // x^-0.25
    }
    float mx = mval;
    #pragma unroll
    for (int o = 32; o >= 1; o >>= 1) mx = fmaxf(mx, __shfl_down(mx, o));
    mx = __shfl(mx, 0);
    if (t < Cc) sm2[t] = Sc * LOG2E * mval * (MAXM / mx);
}

// ---------------------------------------------------------------------------
// K3: main loss — the round-0 hot path VERBATIM (the only structure measured
// at ~100us; all five restructures since landed 157-300us). LDS s_sm staged
// and barrier BEFORE the 21 float4 loads; x[21] tile; two passes over
// registers; no pin asm, no shuffle chains in the hot path. Only the ENDING
// differs from round 0: plain-store partial + fenced last-block finalize
// replaces the 2048-deep contended double-atomic and the extra final_kernel
// launch.
__global__ __launch_bounds__(256, 2) void loss_kernel(const float* __restrict__ pred,
                                                      const int4* __restrict__ t4,
                                                      const float* __restrict__ smg,
                                                      double* __restrict__ partial,
                                                      unsigned int* __restrict__ flag,
                                                      float* __restrict__ out) {
    __shared__ float  s_sm[Cc];
    __shared__ float  wsum[4];
    __shared__ double dsum[4];
    __shared__ bool   s_last;
    int t = threadIdx.x;
    if (t < Cc) s_sm[t] = smg[t];
    __syncthreads();

    int tid = blockIdx.x * 256 + t;           // tid in [0, Nn/4)
    int n0  = tid * 4;
    int b   = n0 >> 18;                       // HWn = 2^18
    int hw  = n0 & (HWn - 1);
    const float4* p4 = (const float4*)(pred + (size_t)b * Cc * HWn + hw);

    // issue all 21 coalesced float4 loads back-to-back (MLP)
    float4 x[Cc];
    #pragma unroll
    for (int c = 0; c < Cc; ++c) x[c] = p4[(size_t)c * (HWn / 4)];

    int4 y4 = t4[tid];
    int ys[4] = {y4.x, y4.y, y4.z, y4.w};
    float smy[4];
    #pragma unroll
    for (int k = 0; k < 4; ++k) smy[k] = s_sm[ys[k]];

    const float S2 = Sc * LOG2E;

    // pass 1: max + target value (base-2 logits), nothing stored
    float mx[4] = {-1e30f, -1e30f, -1e30f, -1e30f};
    float vy[4] = {0.f, 0.f, 0.f, 0.f};
    #pragma unroll
    for (int c = 0; c < Cc; ++c) {
        float xs[4] = {x[c].x, x[c].y, x[c].z, x[c].w};
        #pragma unroll
        for (int k = 0; k < 4; ++k) {
            bool  isy = (c == ys[k]);
            float val = fmaf(S2, xs[k], isy ? -smy[k] : 0.0f);
            mx[k] = fmaxf(mx[k], val);
            vy[k] = isy ? val : vy[k];
        }
    }

    // pass 2: sum of exp2 recomputed from x
    float nll2 = 0.0f;
    #pragma unroll
    for (int k = 0; k < 4; ++k) {
        float cb = -mx[k];                    // non-target: val - mx
        float cy = -smy[k] - mx[k];           // target: val - mx
        float sum = 0.0f;
        #pragma unroll
        for (int c = 0; c < Cc; ++c) {
            float xs = (k == 0) ? x[c].x : (k == 1) ? x[c].y : (k == 2) ? x[c].z : x[c].w;
            sum += exp2f(fmaf(S2, xs, (c == ys[k]) ? cy : cb));
        }
        nll2 += __log2f(sum) + mx[k] - vy[k];
    }
    float nll = nll2 * LN2;

    // wave (64-lane) reduce
    #pragma unroll
    for (int o = 32; o >= 1; o >>= 1) nll += __shfl_down(nll, o);

    int wave = t >> 6;
    int lane = t & 63;
    if (lane == 0) wsum[wave] = nll;
    __syncthreads();
    if (t == 0) {
        float bsum = wsum[0] + wsum[1] + wsum[2] + wsum[3];
        partial[blockIdx.x] = (double)bsum;   // plain store, no contention
        __threadfence();                      // release partial before flag bump
        unsigned done = atomicAdd(flag, 1u);
        s_last = (done == (unsigned)(LOSS_BLOCKS - 1));
    }
    __syncthreads();

    if (s_last) {
        __threadfence();                      // acquire other blocks' partials
        double sm = 0.0;
        for (int i = t; i < LOSS_BLOCKS; i += 256) sm += partial[i];
        #pragma unroll
        for (int o = 32; o >= 1; o >>= 1) sm += __shfl_down(sm, o);
        if ((t & 63) == 0) dsum[t >> 6] = sm;
        __syncthreads();
        if (t == 0)
            out[0] = (float)((dsum[0] + dsum[1] + dsum[2] + dsum[3]) / (double)Nn);
    }
}

extern "C" void kernel_launch(void* const* d_in, const int* in_sizes, int n_in,
                              void* d_out, int out_size, void* d_ws, size_t ws_size,
                              hipStream_t stream) {
    const float* pred   = (const float*)d_in[0];
    const int*   target = (const int*)d_in[1];
    float*       out    = (float*)d_out;

    char* ws = (char*)d_ws;
    int*          counts  = (int*)(ws + WS_COUNTS);
    unsigned int* flag    = (unsigned int*)(ws + WS_FLAG);
    float*        sm      = (float*)(ws + WS_SM);
    double*       partial = (double*)(ws + WS_PART);

    hipMemsetAsync(d_ws, 0, 128, stream);     // zero counts + done-flag

    hist_kernel <<<HIST_BLOCKS, 256, 0, stream>>>((const int4*)target, counts);
    mlist_kernel<<<1,           64,  0, stream>>>(counts, sm);
    loss_kernel <<<LOSS_BLOCKS, 256, 0, stream>>>(pred, (const int4*)target, sm,
                                                  partial, flag, out);
}

// Round 7
// 274.297 us; speedup vs baseline: 1.7641x; 1.1974x over previous
//
#include <hip/hip_runtime.h>

// Problem constants
static constexpr int   Cc  = 21;
static constexpr int   HWn = 512 * 512;         // 262144 = 2^18
static constexpr int   Nn  = 8 * HWn;           // 2097152 pixels
static constexpr float MAXM  = 0.5f;
static constexpr float Sc    = 30.0f;
static constexpr float LOG2E = 1.4426950408889634f;
static constexpr float LN2   = 0.6931471805599453f;

static constexpr int HIST_BLOCKS = 512;               // 512 blk * 256 thr * 4 int4 = Nn
static constexpr int LOSS_BLOCKS = 512;               // 512 blk * 4 waves * 1024 px = Nn

// ws layout (bytes): 0: int counts[21] ; 96: uint done-flag ;
//                    128: float sm2[21] ; 256: double partial[512]
static constexpr int WS_COUNTS = 0;
static constexpr int WS_FLAG   = 96;
static constexpr int WS_SM     = 128;
static constexpr int WS_PART   = 256;

// ---------------------------------------------------------------------------
// K1: class histogram. Per-WAVE LDS sub-histograms, then 21 global atomics
// per block (512-deep per address — negligible tail).
__global__ __launch_bounds__(256) void hist_kernel(const int4* __restrict__ t4,
                                                   int* __restrict__ counts) {
    __shared__ int lh[4][Cc];
    int t = threadIdx.x;
    if (t < 4 * Cc) ((int*)lh)[t] = 0;
    __syncthreads();
    int wave = t >> 6;
    int base = blockIdx.x * (256 * 4) + t;
    #pragma unroll
    for (int i = 0; i < 4; ++i) {
        int4 v = t4[base + i * 256];
        atomicAdd(&lh[wave][v.x], 1);
        atomicAdd(&lh[wave][v.y], 1);
        atomicAdd(&lh[wave][v.z], 1);
        atomicAdd(&lh[wave][v.w], 1);
    }
    __syncthreads();
    if (t < Cc)
        atomicAdd(&counts[t], lh[0][t] + lh[1][t] + lh[2][t] + lh[3][t]);
}

// ---------------------------------------------------------------------------
// K2: m_list -> sm2[c] = S * LOG2E * m_list[c]  (margin in base-2 domain).
__global__ __launch_bounds__(64) void mlist_kernel(const int* __restrict__ counts,
                                                   float* __restrict__ sm2) {
    int t = threadIdx.x;
    float mval = 0.0f;
    if (t < Cc) {
        float cnt = (float)counts[t] + 1e-4f;
        mval = 1.0f / sqrtf(sqrtf(cnt));      // x^-0.25
    }
    float mx = mval;
    #pragma unroll
    for (int o = 32; o >= 1; o >>= 1) mx = fmaxf(mx, __shfl_down(mx, o));
    mx = __shfl(mx, 0);
    if (t < Cc) sm2[t] = Sc * LOG2E * mval * (MAXM / mx);
}

// ---------------------------------------------------------------------------
// Online-softmax update for one element (round-2's verified formulas).
__device__ __forceinline__ void upd1(float x, int y, float smy, int c, float S2,
                                     float& m, float& s, float& v) {
    bool  isy = (c == y);
    float val = fmaf(S2, x, isy ? -smy : 0.0f);
    float mn  = fmaxf(m, val);
    s = fmaf(s, exp2f(m - mn), exp2f(val - mn));
    v = isy ? val : v;
    m = mn;
}

// ---------------------------------------------------------------------------
// K3: main loss — LINEAR-STREAM restructure. Seven measured variants that
// gather 21 class-strided values concurrently per wave all cap at ~1.1 TB/s
// (157-300us) regardless of VGPR/occupancy/staging. Here each wave owns a
// 1024-pixel window and walks classes SEQUENTIALLY: per class one 4KB
// contiguous read (4x dwordx4) — a copy-kernel access pattern (one linear
// stream per wave) — folded into per-pixel online-softmax state that lives
// entirely in registers (16 px/lane: m,s,vy,smy,y + 2 load buffers; all
// indices compile-time constant -> no scratch). Explicit double-buffer,
// `unroll 1` so the schedule stays compact. No LDS state, no barrier in
// the hot loop. Ending: plain-store partial + fenced last-block finalize.
__global__ __launch_bounds__(256, 2) void loss_kernel(const float* __restrict__ pred,
                                                      const int* __restrict__ target,
                                                      const float* __restrict__ smg,
                                                      double* __restrict__ partial,
                                                      unsigned int* __restrict__ flag,
                                                      float* __restrict__ out) {
    __shared__ float  s_sm[Cc];
    __shared__ float  wsum[4];
    __shared__ double dsum[4];
    __shared__ bool   s_last;
    int t = threadIdx.x;
    if (t < Cc) s_sm[t] = smg[t];
    __syncthreads();

    int wave = t >> 6;
    int lane = t & 63;
    int gw   = blockIdx.x * 4 + wave;         // [0, 2048) global wave id
    int P0   = gw << 10;                      // first pixel of this wave's window
    int b    = P0 >> 18;                      // image index (window never straddles)
    int hw0  = P0 & (HWn - 1);
    int poff = lane * 4;                      // lane offset within a 256-px group
    const float* base = pred + (size_t)b * (Cc * HWn) + hw0;

    // per-pixel state: lane owns 16 pixels (4 groups x 4 consecutive)
    float xm[16], xs[16], xv[16], xsm[16];
    int   xy[16];
    #pragma unroll
    for (int j = 0; j < 4; ++j) {
        int4 yv = *(const int4*)&target[P0 + j * 256 + poff];
        xy[4 * j + 0] = yv.x;  xsm[4 * j + 0] = s_sm[yv.x];
        xy[4 * j + 1] = yv.y;  xsm[4 * j + 1] = s_sm[yv.y];
        xy[4 * j + 2] = yv.z;  xsm[4 * j + 2] = s_sm[yv.z];
        xy[4 * j + 3] = yv.w;  xsm[4 * j + 3] = s_sm[yv.w];
    }
    #pragma unroll
    for (int i = 0; i < 16; ++i) { xm[i] = -1e30f; xs[i] = 0.0f; xv[i] = 0.0f; }

    const float S2 = Sc * LOG2E;
    float4 bufA[4], bufB[4];

#define LOADB_(B, c) { const float* pc_ = base + (size_t)(c) * HWn + poff;      \
        B[0] = *(const float4*)(pc_);        B[1] = *(const float4*)(pc_ + 256);\
        B[2] = *(const float4*)(pc_ + 512);  B[3] = *(const float4*)(pc_ + 768); }
#define UPD4_(B, J, c)                                                              \
        upd1(B[J].x, xy[4*(J)+0], xsm[4*(J)+0], (c), S2, xm[4*(J)+0], xs[4*(J)+0], xv[4*(J)+0]); \
        upd1(B[J].y, xy[4*(J)+1], xsm[4*(J)+1], (c), S2, xm[4*(J)+1], xs[4*(J)+1], xv[4*(J)+1]); \
        upd1(B[J].z, xy[4*(J)+2], xsm[4*(J)+2], (c), S2, xm[4*(J)+2], xs[4*(J)+2], xv[4*(J)+2]); \
        upd1(B[J].w, xy[4*(J)+3], xsm[4*(J)+3], (c), S2, xm[4*(J)+3], xs[4*(J)+3], xv[4*(J)+3]);
#define PROC_(B, c) { UPD4_(B, 0, c) UPD4_(B, 1, c) UPD4_(B, 2, c) UPD4_(B, 3, c) }

    LOADB_(bufA, 0);
    #pragma unroll 1
    for (int c = 0; c < 20; c += 2) {
        LOADB_(bufB, c + 1);                  // prefetch odd class
        PROC_(bufA, c);                       // compute even class (hides latency)
        LOADB_(bufA, c + 2);                  // prefetch next even class
        PROC_(bufB, c + 1);
    }
    PROC_(bufA, 20);

#undef LOADB_
#undef UPD4_
#undef PROC_

    // finalize 16 pixels: nll = ln2 * (log2(s) + m - v)
    float nll = 0.0f;
    #pragma unroll
    for (int i = 0; i < 16; ++i) nll += __log2f(xs[i]) + xm[i] - xv[i];
    nll *= LN2;

    // wave (64-lane) reduce
    #pragma unroll
    for (int o = 32; o >= 1; o >>= 1) nll += __shfl_down(nll, o);

    if (lane == 0) wsum[wave] = nll;
    __syncthreads();
    if (t == 0) {
        float bsum = wsum[0] + wsum[1] + wsum[2] + wsum[3];
        partial[blockIdx.x] = (double)bsum;   // plain store, no contention
        __threadfence();                      // release partial before flag bump
        unsigned done = atomicAdd(flag, 1u);
        s_last = (done == (unsigned)(LOSS_BLOCKS - 1));
    }
    __syncthreads();

    if (s_last) {
        __threadfence();                      // acquire other blocks' partials
        double sm = 0.0;
        for (int i = t; i < LOSS_BLOCKS; i += 256) sm += partial[i];
        #pragma unroll
        for (int o = 32; o >= 1; o >>= 1) sm += __shfl_down(sm, o);
        if ((t & 63) == 0) dsum[t >> 6] = sm;
        __syncthreads();
        if (t == 0)
            out[0] = (float)((dsum[0] + dsum[1] + dsum[2] + dsum[3]) / (double)Nn);
    }
}

extern "C" void kernel_launch(void* const* d_in, const int* in_sizes, int n_in,
                              void* d_out, int out_size, void* d_ws, size_t ws_size,
                              hipStream_t stream) {
    const float* pred   = (const float*)d_in[0];
    const int*   target = (const int*)d_in[1];
    float*       out    = (float*)d_out;

    char* ws = (char*)d_ws;
    int*          counts  = (int*)(ws + WS_COUNTS);
    unsigned int* flag    = (unsigned int*)(ws + WS_FLAG);
    float*        sm      = (float*)(ws + WS_SM);
    double*       partial = (double*)(ws + WS_PART);

    hipMemsetAsync(d_ws, 0, 128, stream);     // zero counts + done-flag

    hist_kernel <<<HIST_BLOCKS, 256, 0, stream>>>((const int4*)target, counts);
    mlist_kernel<<<1,           64,  0, stream>>>(counts, sm);
    loss_kernel <<<LOSS_BLOCKS, 256, 0, stream>>>(pred, target, sm,
                                                  partial, flag, out);
}